// Round 4
// baseline (299.910 us; speedup 1.0000x reference)
//
#include <hip/hip_runtime.h>

// Problem constants: B=256, NT=301, D=96, NSEG=50
// linspace(1,301,51) -> segment s = rows [6s, 6s+6] (7 rows).
// v4: ONE BLOCK PER (batch, half) -- 512 blocks x 512 threads.
//   Each block stages 151 rows x 96 cols col-major in LDS (once), then two
//   256-thread groups sweep 25 segments (12-13 each) with v3's register
//   algebra. Theory: 12800-tiny-block structure was overhead-bound (two
//   neutral inner-loop rewrites); amortize block setup 25x.
#define BB 256
#define NT_ 301
#define DD 96
#define NSEG 50
#define NTRI (DD * (DD - 1) / 2)   // 4560
#define OUTD (DD + NTRI)           // 4656
#define HSEG 25                    // segments per block
#define HROWS 151                  // rows staged per block (6*25+1)
#define CSTR 154                   // LDS column stride (floats): even (8B align
                                   // for float2) and 154%32=26 -> 26*tx mod 32
                                   // hits 16 distinct banks for tx=0..15.

// Levy area, algebraically reduced (si[t]*sj[t] cross terms cancel):
//   A_ij = 0.5 * [ sum_{t=1..5} (si[t]*sj[t+1] - si[t+1]*sj[t])
//                  + sj[0]*(si[6]-si[1]) - si[0]*(sj[6]-sj[1]) ]
// 0.5 folded into the per-thread row cache.

__global__ __launch_bounds__(512)
void logsig_kernel(const float* __restrict__ inp, float* __restrict__ out) {
    const int bh = blockIdx.x;          // 0 .. 511
    const int b  = bh >> 1;
    const int h  = bh & 1;

    // colp[d*CSTR + t] = inp[b, h*150 + t, d], t in [0,151)
    __shared__ float colp[DD * CSTR];   // 96*154*4 = 59136 B

    const float* __restrict__ src = inp + ((size_t)b * NT_ + (size_t)(150 * h)) * DD;
    for (int idx = threadIdx.x; idx < HROWS * DD; idx += 512) {
        const int r = idx / DD;         // magic-mul (constant divisor)
        const int c = idx - r * DD;
        colp[c * CSTR + r] = src[idx];
    }
    __syncthreads();

    const int g    = threadIdx.x >> 8;  // group 0/1, each 256 threads
    const int t256 = threadIdx.x & 255;
    const int ty   = t256 >> 4;         // 0..15
    const int tx   = t256 & 15;         // 0..15

    // triu(k=1) row bases (segment-independent)
    int rowoff[6];
    #pragma unroll
    for (int ti = 0; ti < 6; ++ti) {
        const int i = 16 * ti + ty;
        rowoff[ti] = DD + (i * (2 * DD - 1 - i)) / 2 - i - 1;
    }

    #pragma unroll 1
    for (int sl = g; sl < HSEG; sl += 2) {
        const int t0 = 6 * sl;          // even -> 8B-aligned float2 reads
        float* __restrict__ o = out + ((size_t)(b * NSEG + h * HSEG + sl)) * OUTD;

        // Row cache: 6 rows i = 16*ti+ty, pre-scaled by 0.5 (48 VGPRs).
        float rs[6][8];
        #pragma unroll
        for (int ti = 0; ti < 6; ++ti) {
            const int i = 16 * ti + ty;
            const float2* __restrict__ p =
                reinterpret_cast<const float2*>(&colp[i * CSTR + t0]);
            const float2 v0 = p[0], v1 = p[1], v2 = p[2];
            const float  v6 = colp[i * CSTR + t0 + 6];
            rs[ti][0] = 0.5f * v0.x; rs[ti][1] = 0.5f * v0.y;
            rs[ti][2] = 0.5f * v1.x; rs[ti][3] = 0.5f * v1.y;
            rs[ti][4] = 0.5f * v2.x; rs[ti][5] = 0.5f * v2.y;
            rs[ti][6] = 0.5f * v6;
            rs[ti][7] = rs[ti][6] - rs[ti][1];             // 0.5*(s6-s1)
        }

        #pragma unroll
        for (int tj = 0; tj < 6; ++tj) {
            const int j = 16 * tj + tx;
            const float2* __restrict__ q =
                reinterpret_cast<const float2*>(&colp[j * CSTR + t0]);
            const float2 w0 = q[0], w1 = q[1], w2 = q[2];
            const float  c0 = w0.x, c1 = w0.y, c2 = w1.x, c3 = w1.y;
            const float  c4 = w2.x, c5 = w2.y;
            const float  c6 = colp[j * CSTR + t0 + 6];
            const float  uj = c6 - c1;
            if (ty == 0)
                o[j] = c6 - c0;                            // lvl1 (unscaled)
            #pragma unroll
            for (int ti = 0; ti <= tj; ++ti) {
                // full tiles (ti<tj): always; diagonal: j>i <=> tx>ty
                if (ti < tj || tx > ty) {
                    float acc  = rs[ti][7] * c0 - rs[ti][0] * uj;
                    acc += rs[ti][1] * c2 - rs[ti][2] * c1;
                    acc += rs[ti][2] * c3 - rs[ti][3] * c2;
                    acc += rs[ti][3] * c4 - rs[ti][4] * c3;
                    acc += rs[ti][4] * c5 - rs[ti][5] * c4;
                    acc += rs[ti][5] * c6 - rs[ti][6] * c5;
                    o[rowoff[ti] + j] = acc;
                }
            }
        }
    }
}

extern "C" void kernel_launch(void* const* d_in, const int* in_sizes, int n_in,
                              void* d_out, int out_size, void* d_ws, size_t ws_size,
                              hipStream_t stream) {
    const float* inp = (const float*)d_in[0];
    float* out = (float*)d_out;
    logsig_kernel<<<2 * BB, 512, 0, stream>>>(inp, out);
}